// Round 3
// baseline (101.313 us; speedup 1.0000x reference)
//
#include <hip/hip_runtime.h>
#include <stdint.h>

#define HH   96
#define WW   96
#define HW   9216
#define CIN  256
#define COUT 256
#define NB   2      // batch
#define NG   4      // groups
#define CG   64     // channels per group
#define KK   9
#define KTOT 2304   // CIN*KK
#define KB   288    // KTOT/8
#define TS   8      // sampler pixel tile side
#define WIN  12     // staged window side (TS + 4)
#define SCH  32     // sampler channels per block

typedef __attribute__((ext_vector_type(8))) short short8;
typedef __attribute__((ext_vector_type(4))) float f32x4;
typedef __attribute__((ext_vector_type(4))) uint32_t u32x4;

__device__ __forceinline__ uint32_t f2bf(float f) {
    uint32_t u = __builtin_bit_cast(uint32_t, f);
    return (u + 0x7fffu + ((u >> 16) & 1u)) >> 16;   // RNE
}

// ---------------------------------------------------------------------------
// Kernel 1: w_deform (COUT x CIN x 9 fp32) -> bf16, blocked [my][kb][o%128][8]
// K-order is kk-major: k' = kk*256 + c  (must match sampler's S layout)
// ---------------------------------------------------------------------------
__global__ __launch_bounds__(256) void prep_A(const float* __restrict__ wd,
                                              uint16_t* __restrict__ Ablk) {
    int t  = blockIdx.x * 256 + threadIdx.x;   // 73728 = 256*288
    int kb = t % KB;
    int o  = t / KB;
    int kkA = kb >> 5;            // (kb*8)/256
    int c0A = (kb & 31) * 8;      // (kb*8)%256
    const float* src = wd + (size_t)o * KTOT + c0A * KK + kkA;
    float a[8];
#pragma unroll
    for (int e = 0; e < 8; ++e) a[e] = src[e * KK];
    int my = o >> 7, ol = o & 127;
    uint16_t* dst = Ablk + (((size_t)my * KB + kb) * 128 + ol) * 8;
    u32x4 v;
    v.x = f2bf(a[0]) | (f2bf(a[1]) << 16);
    v.y = f2bf(a[2]) | (f2bf(a[3]) << 16);
    v.z = f2bf(a[4]) | (f2bf(a[5]) << 16);
    v.w = f2bf(a[6]) | (f2bf(a[7]) << 16);
    *(u32x4*)dst = v;
}

// ---------------------------------------------------------------------------
// Kernel 2: offsets + bilinear sampling -> S[b][kb][p][8] bf16 (kk-major K)
// block = 8x8 pixel tile x 32 channels (2 waves); window staged in LDS
// (19.6 KB -> ~8 blocks/CU resident). Separable clamp-aware pair weights,
// corner coefficients hoisted per kk. Global fallback for offsets escaping
// the window (never taken at this data scale; exec-masked).
// ---------------------------------------------------------------------------
__global__ __launch_bounds__(128) void sampler(const float* __restrict__ feature,
                                               const float* __restrict__ pred,
                                               const float* __restrict__ woff,
                                               uint16_t* __restrict__ S) {
    __shared__ float ft[SCH * WIN * WIN];  // 18432 B
    __shared__ float wo[NG * KK * 2 * 4];  // 1152 B

    int tid = threadIdx.x;
    int cb = blockIdx.y, b = blockIdx.z;
    int ch0 = cb * SCH;                    // global channel base
    int g = ch0 >> 6;                      // group
    int ty = blockIdx.x / (WW / TS), tx = blockIdx.x % (WW / TS);
    int r0 = ty * TS, c0 = tx * TS;
    int rlo = min(max(r0 - 2, 0), HH - WIN);
    int clo = min(max(c0 - 2, 0), WW - WIN);

    for (int i = tid; i < NG * KK * 2 * 4; i += 128) wo[i] = woff[i];

    const float* fg = feature + ((size_t)(b * CIN + ch0)) * HW;
    for (int e = tid; e < SCH * WIN * WIN; e += 128) {
        int ch = e / (WIN * WIN);
        int re = e - ch * (WIN * WIN);
        int rr = re / WIN, cc = re - rr * WIN;
        ft[e] = fg[(size_t)ch * HW + (rlo + rr) * WW + clo + cc];
    }
    __syncthreads();

    int lane = tid & 63, wv = tid >> 6;    // wv in {0,1}
    int lr = lane >> 3, lc = lane & 7;
    int hy = r0 + lr, hx = c0 + lc;
    int p = hy * WW + hx;
    float4 ps4 = *(const float4*)(pred + ((size_t)b * HW + p) * 4);

    const float* ftw = ft + (wv * 16) * (WIN * WIN);
    const float* fgw = fg + (size_t)(wv * 16) * HW;     // fallback base
    int kb_base = ((ch0 + wv * 16) >> 3);

#pragma unroll
    for (int kk = 0; kk < KK; ++kk) {
        const float* wy = &wo[(g * KK + kk) * 8];
        float offy = ps4.x * wy[0] + ps4.y * wy[1] + ps4.z * wy[2] + ps4.w * wy[3];
        float offx = ps4.x * wy[4] + ps4.y * wy[5] + ps4.z * wy[6] + ps4.w * wy[7];
        float py = (float)(hy - 1 + kk / 3) + offy;
        float px = (float)(hx - 1 + kk % 3) + offx;
        float fy = floorf(py), fx = floorf(px);
        int y0 = (int)fy, x0 = (int)fx;
        float ly = py - fy, lx = px - fx;
        int r = min(max(y0, 0), HH - 2);
        int q = min(max(x0, 0), WW - 2);
        float wyA = (y0 == r) ? (1.f - ly) : ((y0 == -1) ? ly : 0.f);
        float wyB = (y0 == r) ? ly : ((y0 == HH - 1) ? (1.f - ly) : 0.f);
        float wxA = (x0 == q) ? (1.f - lx) : ((x0 == -1) ? lx : 0.f);
        float wxB = (x0 == q) ? lx : ((x0 == WW - 1) ? (1.f - lx) : 0.f);
        float c00 = wyA * wxA, c01 = wyA * wxB;
        float c10 = wyB * wxA, c11 = wyB * wxB;

        bool fast = (r >= rlo) & (r <= rlo + WIN - 2) &
                    (q >= clo) & (q <= clo + WIN - 2);

        uint16_t* Sp = S + (((size_t)b * KB + (kk * 32 + kb_base)) * HW + p) * 8;

        if (fast) {
            int base = (r - rlo) * WIN + (q - clo);
#pragma unroll
            for (int ch8 = 0; ch8 < 2; ++ch8) {
                uint32_t pk[4];
#pragma unroll
                for (int e = 0; e < 8; ++e) {
                    const float* fp = ftw + (ch8 * 8 + e) * (WIN * WIN) + base;
                    float v = c00 * fp[0] + c01 * fp[1] + c10 * fp[WIN] + c11 * fp[WIN + 1];
                    uint32_t bfv = f2bf(v);
                    if (e & 1) pk[e >> 1] |= bfv << 16;
                    else       pk[e >> 1]  = bfv;
                }
                u32x4 vv = {pk[0], pk[1], pk[2], pk[3]};
                *(u32x4*)(Sp) = vv;
                Sp += (size_t)HW * 8;
            }
        } else {
            size_t gb = (size_t)r * WW + q;
#pragma unroll
            for (int ch8 = 0; ch8 < 2; ++ch8) {
                uint32_t pk[4];
#pragma unroll
                for (int e = 0; e < 8; ++e) {
                    const float* fp = fgw + (size_t)(ch8 * 8 + e) * HW + gb;
                    float v = c00 * fp[0] + c01 * fp[1] + c10 * fp[WW] + c11 * fp[WW + 1];
                    uint32_t bfv = f2bf(v);
                    if (e & 1) pk[e >> 1] |= bfv << 16;
                    else       pk[e >> 1]  = bfv;
                }
                u32x4 vv = {pk[0], pk[1], pk[2], pk[3]};
                *(u32x4*)(Sp) = vv;
                Sp += (size_t)HW * 8;
            }
        }
    }
}

// ---------------------------------------------------------------------------
// Kernel 3: out[b,o,p] = relu( sum_k A[o,k] * S[k,p] )  (bf16 MFMA 16x16x32)
// 128x128 tile, BK=32, 4 waves each 64x64. T3/T4 depth-2 pipeline:
// double-buffered LDS, counted s_waitcnt vmcnt(4) + raw s_barrier so the
// next K-step's global_load_lds stay in flight across barriers.
// ---------------------------------------------------------------------------
__global__ __launch_bounds__(256) void gemm_kernel(const uint16_t* __restrict__ S,
                                                   const uint16_t* __restrict__ Ablk,
                                                   float* __restrict__ out) {
    __shared__ uint16_t sA[2][4 * 128 * 8];   // [buf][kc][o][8]
    __shared__ uint16_t sB[2][4 * 128 * 8];   // [buf][kc][p][8]

    int tid = threadIdx.x;
    int lane = tid & 63, wv = tid >> 6;
    int wr = wv >> 1, wc = wv & 1;
    int col0 = blockIdx.x * 128;           // p tile (72)
    int my   = blockIdx.y;                 // o tile (2)
    int b    = blockIdx.z;

    const uint16_t* Ag = Ablk + (size_t)my * KB * 128 * 8;
    const uint16_t* Bg = S    + (size_t)b  * KB * HW  * 8;

    f32x4 acc[4][4];
#pragma unroll
    for (int m = 0; m < 4; ++m)
#pragma unroll
        for (int n = 0; n < 4; ++n) acc[m][n] = (f32x4){0.f, 0.f, 0.f, 0.f};

    int kc = lane >> 4, il = lane & 15;
    const int NT = KTOT / 32;              // 72

    // wave wv stages k-chunk row (t*4 + wv) of both A and B (4 loads/wave)
    auto STAGE = [&](int t, int buf) {
        const uint16_t* ga = Ag + ((size_t)(t * 4 + wv) * 128) * 8;
        uint16_t* la = &sA[buf][wv * 128 * 8];
        const uint16_t* gb = Bg + ((size_t)(t * 4 + wv) * HW + col0) * 8;
        uint16_t* lb = &sB[buf][wv * 128 * 8];
#pragma unroll
        for (int h = 0; h < 2; ++h) {
            __builtin_amdgcn_global_load_lds(
                (const __attribute__((address_space(1))) uint32_t*)(ga + (h * 64 + lane) * 8),
                (__attribute__((address_space(3))) uint32_t*)(la + h * 64 * 8),
                16, 0, 0);
            __builtin_amdgcn_global_load_lds(
                (const __attribute__((address_space(1))) uint32_t*)(gb + (h * 64 + lane) * 8),
                (__attribute__((address_space(3))) uint32_t*)(lb + h * 64 * 8),
                16, 0, 0);
        }
    };

    STAGE(0, 0);
    STAGE(1, 1);

    for (int t = 0; t < NT; ++t) {
        int cur = t & 1;
        // wait for step t's 4 loads (step t+1's 4 remain in flight), rendezvous
        if (t < NT - 1) {
            asm volatile("s_waitcnt vmcnt(4)\n\ts_barrier" ::: "memory");
        } else {
            asm volatile("s_waitcnt vmcnt(0)\n\ts_barrier" ::: "memory");
        }
        __builtin_amdgcn_sched_barrier(0);

        short8 af[4], bf[4];
#pragma unroll
        for (int m = 0; m < 4; ++m)
            af[m] = *(const short8*)(&sA[cur][((kc * 128) + (wr * 64 + m * 16 + il)) * 8]);
#pragma unroll
        for (int n = 0; n < 4; ++n)
            bf[n] = *(const short8*)(&sB[cur][((kc * 128) + (wc * 64 + n * 16 + il)) * 8]);

#pragma unroll
        for (int m = 0; m < 4; ++m)
#pragma unroll
            for (int n = 0; n < 4; ++n)
                acc[m][n] = __builtin_amdgcn_mfma_f32_16x16x32_bf16(af[m], bf[n], acc[m][n], 0, 0, 0);

        // all waves done reading buf[cur] (lgkmcnt drained), then reuse it
        asm volatile("s_waitcnt lgkmcnt(0)\n\ts_barrier" ::: "memory");
        __builtin_amdgcn_sched_barrier(0);
        if (t + 2 < NT) STAGE(t + 2, cur);
    }

    int r4 = (lane >> 4) * 4;
    size_t obase = ((size_t)b * COUT + my * 128 + wr * 64) * HW + col0 + wc * 64;
#pragma unroll
    for (int m = 0; m < 4; ++m)
#pragma unroll
        for (int n = 0; n < 4; ++n)
#pragma unroll
            for (int r = 0; r < 4; ++r) {
                float v = acc[m][n][r];
                v = v > 0.f ? v : 0.f;
                out[obase + (size_t)(m * 16 + r4 + r) * HW + n * 16 + il] = v;
            }
}

// ---------------------------------------------------------------------------
extern "C" void kernel_launch(void* const* d_in, const int* in_sizes, int n_in,
                              void* d_out, int out_size, void* d_ws, size_t ws_size,
                              hipStream_t stream) {
    (void)in_sizes; (void)n_in; (void)out_size; (void)ws_size;
    const float* feature = (const float*)d_in[0];
    const float* pred    = (const float*)d_in[1];
    const float* woff    = (const float*)d_in[2];
    const float* wdef    = (const float*)d_in[3];
    float* out = (float*)d_out;

    const size_t S_BYTES = (size_t)NB * KB * HW * 8 * 2;   // 84,934,656
    uint16_t* S    = (uint16_t*)d_ws;
    uint16_t* Ablk = (uint16_t*)((char*)d_ws + S_BYTES);

    hipLaunchKernelGGL(prep_A, dim3(288), dim3(256), 0, stream, wdef, Ablk);
    hipLaunchKernelGGL(sampler, dim3((HH / TS) * (WW / TS), CIN / SCH, NB), dim3(128), 0, stream,
                       feature, pred, woff, S);
    hipLaunchKernelGGL(gemm_kernel, dim3(HW / 128, 2, NB), dim3(256), 0, stream,
                       S, Ablk, out);
}

// Round 5
// 99.946 us; speedup vs baseline: 1.0137x; 1.0137x over previous
//
#include <hip/hip_runtime.h>
#include <hip/hip_bf16.h>
#include <stdint.h>

#define HH   96
#define WW   96
#define HW   9216
#define CIN  256
#define COUT 256
#define NB   2      // batch
#define NG   4      // groups
#define CG   64     // channels per group
#define KK   9
#define KTOT 2304   // CIN*KK
#define KB   288    // KTOT/8
#define TS   8      // sampler pixel tile side
#define WIN  12     // staged window side (TS + 4)
#define SCH  32     // sampler channels per block

typedef __attribute__((ext_vector_type(8))) short short8;
typedef __attribute__((ext_vector_type(4))) float f32x4;
typedef __attribute__((ext_vector_type(4))) uint32_t u32x4;

__device__ __forceinline__ uint32_t pk2bf(float v0, float v1) {
    __hip_bfloat162 h = __float22bfloat162_rn(make_float2(v0, v1));  // v_cvt_pk_bf16_f32
    uint32_t u;
    __builtin_memcpy(&u, &h, 4);
    return u;
}

// ---------------------------------------------------------------------------
// Kernel 1: w_deform (COUT x CIN x 9 fp32) -> bf16, blocked [my][kb][o%128][8]
// K-order is kk-major: k' = kk*256 + c  (must match sampler's S layout)
// ---------------------------------------------------------------------------
__global__ __launch_bounds__(256) void prep_A(const float* __restrict__ wd,
                                              uint16_t* __restrict__ Ablk) {
    int t  = blockIdx.x * 256 + threadIdx.x;   // 73728 = 256*288
    int kb = t % KB;
    int o  = t / KB;
    int kkA = kb >> 5;            // (kb*8)/256
    int c0A = (kb & 31) * 8;      // (kb*8)%256
    const float* src = wd + (size_t)o * KTOT + c0A * KK + kkA;
    float a[8];
#pragma unroll
    for (int e = 0; e < 8; ++e) a[e] = src[e * KK];
    int my = o >> 7, ol = o & 127;
    uint16_t* dst = Ablk + (((size_t)my * KB + kb) * 128 + ol) * 8;
    u32x4 v;
    v.x = pk2bf(a[0], a[1]);
    v.y = pk2bf(a[2], a[3]);
    v.z = pk2bf(a[4], a[5]);
    v.w = pk2bf(a[6], a[7]);
    *(u32x4*)dst = v;
}

// ---------------------------------------------------------------------------
// Kernel 2: offsets + bilinear sampling -> S[b][kb][p][8] bf16 (kk-major K)
// block = 8x8 pixel tile x 32 channels (2 waves). Feature window in LDS.
// Bilinear weights + clamped indices precomputed ONCE per (px,kk) into an
// LDS table (removes the serial clamp/select chain from the 9x inner loop).
// Global fallback for offsets escaping the window (never taken here).
// ---------------------------------------------------------------------------
__global__ __launch_bounds__(128) void sampler(const float* __restrict__ feature,
                                               const float* __restrict__ pred,
                                               const float* __restrict__ woff,
                                               uint16_t* __restrict__ S) {
    __shared__ float ft[SCH * WIN * WIN];  // 18432 B
    __shared__ float tw0[576], tw1[576], tw2[576], tw3[576];  // 9216 B
    __shared__ int   tbf[576], tbg[576];                      // 4608 B

    int tid = threadIdx.x;
    int cb = blockIdx.y, b = blockIdx.z;
    int ch0 = cb * SCH;                    // global channel base
    int g = ch0 >> 6;                      // group
    int ty = blockIdx.x / (WW / TS), tx = blockIdx.x % (WW / TS);
    int r0 = ty * TS, c0 = tx * TS;
    int rlo = min(max(r0 - 2, 0), HH - WIN);
    int clo = min(max(c0 - 2, 0), WW - WIN);

    // ---- stage feature window [ch][r][q] (fp32)
    const float* fg = feature + ((size_t)(b * CIN + ch0)) * HW;
    for (int e = tid; e < SCH * WIN * WIN; e += 128) {
        int ch = e / (WIN * WIN);
        int re = e - ch * (WIN * WIN);
        int rr = re / WIN, cc = re - rr * WIN;
        ft[e] = fg[(size_t)ch * HW + (rlo + rr) * WW + clo + cc];
    }

    // ---- weight/index table: entry i = kk*64 + px
    for (int i = tid; i < 576; i += 128) {
        int kk = i >> 6, px = i & 63;
        int hy = r0 + (px >> 3), hx = c0 + (px & 7);
        float4 ps4 = *(const float4*)(pred + ((size_t)b * HW + hy * WW + hx) * 4);
        const float* wy = woff + (g * KK + kk) * 8;
        float offy = ps4.x * wy[0] + ps4.y * wy[1] + ps4.z * wy[2] + ps4.w * wy[3];
        float offx = ps4.x * wy[4] + ps4.y * wy[5] + ps4.z * wy[6] + ps4.w * wy[7];
        float py = (float)(hy - 1 + kk / 3) + offy;
        float px_ = (float)(hx - 1 + kk % 3) + offx;
        float fy = floorf(py), fx = floorf(px_);
        int y0 = (int)fy, x0 = (int)fx;
        float ly = py - fy, lx = px_ - fx;
        int r = min(max(y0, 0), HH - 2);
        int q = min(max(x0, 0), WW - 2);
        float wyA = (y0 == r) ? (1.f - ly) : ((y0 == -1) ? ly : 0.f);
        float wyB = (y0 == r) ? ly : ((y0 == HH - 1) ? (1.f - ly) : 0.f);
        float wxA = (x0 == q) ? (1.f - lx) : ((x0 == -1) ? lx : 0.f);
        float wxB = (x0 == q) ? lx : ((x0 == WW - 1) ? (1.f - lx) : 0.f);
        tw0[i] = wyA * wxA; tw1[i] = wyA * wxB;
        tw2[i] = wyB * wxA; tw3[i] = wyB * wxB;
        bool fast = (r >= rlo) & (r <= rlo + WIN - 2) &
                    (q >= clo) & (q <= clo + WIN - 2);
        tbf[i] = fast ? ((r - rlo) * WIN + (q - clo)) : -1;
        tbg[i] = r * WW + q;
    }
    __syncthreads();

    int lane = tid & 63, wv = tid >> 6;    // wv in {0,1}
    int p = (r0 + (lane >> 3)) * WW + c0 + (lane & 7);
    const float* ftw = ft + (wv * 16) * (WIN * WIN);
    const float* fgw = fg + (size_t)(wv * 16) * HW;     // fallback base
    int kb_base = cb * 4 + wv * 2;

#pragma unroll
    for (int kk = 0; kk < KK; ++kk) {
        int i = kk * 64 + lane;
        float c00 = tw0[i], c01 = tw1[i], c10 = tw2[i], c11 = tw3[i];
        int fb = tbf[i], gbi = tbg[i];

        uint16_t* Sp = S + (((size_t)b * KB + (kk * 32 + kb_base)) * HW + p) * 8;

        if (fb >= 0) {
#pragma unroll
            for (int ch8 = 0; ch8 < 2; ++ch8) {
                uint32_t pk[4];
#pragma unroll
                for (int ep = 0; ep < 4; ++ep) {
                    const float* f0 = ftw + (ch8 * 8 + 2 * ep) * (WIN * WIN) + fb;
                    const float* f1 = f0 + (WIN * WIN);
                    float v0 = c00 * f0[0] + c01 * f0[1] + c10 * f0[WIN] + c11 * f0[WIN + 1];
                    float v1 = c00 * f1[0] + c01 * f1[1] + c10 * f1[WIN] + c11 * f1[WIN + 1];
                    pk[ep] = pk2bf(v0, v1);
                }
                u32x4 vv = {pk[0], pk[1], pk[2], pk[3]};
                *(u32x4*)(Sp) = vv;
                Sp += (size_t)HW * 8;
            }
        } else {
#pragma unroll
            for (int ch8 = 0; ch8 < 2; ++ch8) {
                uint32_t pk[4];
#pragma unroll
                for (int ep = 0; ep < 4; ++ep) {
                    const float* f0 = fgw + (size_t)(ch8 * 8 + 2 * ep) * HW + gbi;
                    const float* f1 = f0 + HW;
                    float v0 = c00 * f0[0] + c01 * f0[1] + c10 * f0[WW] + c11 * f0[WW + 1];
                    float v1 = c00 * f1[0] + c01 * f1[1] + c10 * f1[WW] + c11 * f1[WW + 1];
                    pk[ep] = pk2bf(v0, v1);
                }
                u32x4 vv = {pk[0], pk[1], pk[2], pk[3]};
                *(u32x4*)(Sp) = vv;
                Sp += (size_t)HW * 8;
            }
        }
    }
}

// ---------------------------------------------------------------------------
// Kernel 3: out[b,o,p] = relu( sum_k A[o,k] * S[k,p] )  (bf16 MFMA 16x16x32)
// 128x64 tile -> 576 blocks (2-3 resident/CU, real TLP). 4 waves each 64x32.
// Depth-2 pipeline: double-buffered LDS, counted s_waitcnt vmcnt(3) so the
// next K-step's 3 global_load_lds stay in flight across barriers.
// ---------------------------------------------------------------------------
__global__ __launch_bounds__(256) void gemm_kernel(const uint16_t* __restrict__ S,
                                                   const uint16_t* __restrict__ Ablk,
                                                   float* __restrict__ out) {
    __shared__ uint16_t sA[2][4 * 128 * 8];   // 8 KB per buf
    __shared__ uint16_t sB[2][4 * 64 * 8];    // 4 KB per buf

    int tid = threadIdx.x;
    int lane = tid & 63, wv = tid >> 6;
    int wr = wv >> 1, wc = wv & 1;
    int col0 = blockIdx.x * 64;            // p tile (144)
    int my   = blockIdx.y;                 // o tile (2)
    int b    = blockIdx.z;

    const uint16_t* Ag = Ablk + (size_t)my * KB * 128 * 8;
    const uint16_t* Bg = S    + (size_t)b  * KB * HW  * 8;

    f32x4 acc[4][2];
#pragma unroll
    for (int m = 0; m < 4; ++m)
#pragma unroll
        for (int n = 0; n < 2; ++n) acc[m][n] = (f32x4){0.f, 0.f, 0.f, 0.f};

    int kc = lane >> 4, il = lane & 15;
    const int NT = KTOT / 32;              // 72

    // wave wv stages k-chunk row (t*4 + wv): A = 2 loads, B = 1 load
    auto STAGE = [&](int t, int buf) {
        const uint16_t* ga = Ag + ((size_t)(t * 4 + wv) * 128) * 8;
        uint16_t* la = &sA[buf][wv * 128 * 8];
#pragma unroll
        for (int h = 0; h < 2; ++h) {
            __builtin_amdgcn_global_load_lds(
                (const __attribute__((address_space(1))) uint32_t*)(ga + (h * 64 + lane) * 8),
                (__attribute__((address_space(3))) uint32_t*)(la + h * 64 * 8),
                16, 0, 0);
        }
        const uint16_t* gb = Bg + ((size_t)(t * 4 + wv) * HW + col0) * 8;
        uint16_t* lb = &sB[buf][wv * 64 * 8];
        __builtin_amdgcn_global_load_lds(
            (const __attribute__((address_space(1))) uint32_t*)(gb + lane * 8),
            (__attribute__((address_space(3))) uint32_t*)(lb),
            16, 0, 0);
    };

    STAGE(0, 0);
    STAGE(1, 1);

    for (int t = 0; t < NT; ++t) {
        int cur = t & 1;
        if (t < NT - 1) {
            asm volatile("s_waitcnt vmcnt(3)\n\ts_barrier" ::: "memory");
        } else {
            asm volatile("s_waitcnt vmcnt(0)\n\ts_barrier" ::: "memory");
        }
        __builtin_amdgcn_sched_barrier(0);

        short8 af[4], bf[2];
#pragma unroll
        for (int m = 0; m < 4; ++m)
            af[m] = *(const short8*)(&sA[cur][((kc * 128) + (wr * 64 + m * 16 + il)) * 8]);
#pragma unroll
        for (int n = 0; n < 2; ++n)
            bf[n] = *(const short8*)(&sB[cur][((kc * 64) + (wc * 32 + n * 16 + il)) * 8]);

#pragma unroll
        for (int m = 0; m < 4; ++m)
#pragma unroll
            for (int n = 0; n < 2; ++n)
                acc[m][n] = __builtin_amdgcn_mfma_f32_16x16x32_bf16(af[m], bf[n], acc[m][n], 0, 0, 0);

        // all waves done reading buf[cur], then refill it for step t+2
        asm volatile("s_waitcnt lgkmcnt(0)\n\ts_barrier" ::: "memory");
        __builtin_amdgcn_sched_barrier(0);
        if (t + 2 < NT) STAGE(t + 2, cur);
    }

    int r4 = (lane >> 4) * 4;
    size_t obase = ((size_t)b * COUT + my * 128 + wr * 64) * HW + col0 + wc * 32;
#pragma unroll
    for (int m = 0; m < 4; ++m)
#pragma unroll
        for (int n = 0; n < 2; ++n)
#pragma unroll
            for (int r = 0; r < 4; ++r) {
                float v = acc[m][n][r];
                v = v > 0.f ? v : 0.f;
                out[obase + (size_t)(m * 16 + r4 + r) * HW + n * 16 + il] = v;
            }
}

// ---------------------------------------------------------------------------
extern "C" void kernel_launch(void* const* d_in, const int* in_sizes, int n_in,
                              void* d_out, int out_size, void* d_ws, size_t ws_size,
                              hipStream_t stream) {
    (void)in_sizes; (void)n_in; (void)out_size; (void)ws_size;
    const float* feature = (const float*)d_in[0];
    const float* pred    = (const float*)d_in[1];
    const float* woff    = (const float*)d_in[2];
    const float* wdef    = (const float*)d_in[3];
    float* out = (float*)d_out;

    const size_t S_BYTES = (size_t)NB * KB * HW * 8 * 2;   // 84,934,656
    uint16_t* S    = (uint16_t*)d_ws;
    uint16_t* Ablk = (uint16_t*)((char*)d_ws + S_BYTES);

    hipLaunchKernelGGL(prep_A, dim3(288), dim3(256), 0, stream, wdef, Ablk);
    hipLaunchKernelGGL(sampler, dim3((HH / TS) * (WW / TS), CIN / SCH, NB), dim3(128), 0, stream,
                       feature, pred, woff, S);
    hipLaunchKernelGGL(gemm_kernel, dim3(HW / 64, 2, NB), dim3(256), 0, stream,
                       S, Ablk, out);
}

// Round 6
// 86.283 us; speedup vs baseline: 1.1742x; 1.1584x over previous
//
#include <hip/hip_runtime.h>
#include <hip/hip_bf16.h>
#include <stdint.h>

#define HH   96
#define WW   96
#define HW   9216
#define CIN  256
#define COUT 256
#define NB   2      // batch
#define NG   4      // groups
#define CG   64     // channels per group
#define KK   9
#define KTOT 2304   // CIN*KK
#define KB   288    // KTOT/8
#define TS   8      // sampler pixel tile side
#define WIN  12     // staged window side (TS + 4)
#define SCH  32     // sampler channels per block (one 8-ch pass per wave)

typedef __attribute__((ext_vector_type(8))) short short8;
typedef __attribute__((ext_vector_type(4))) float f32x4;
typedef __attribute__((ext_vector_type(4))) uint32_t u32x4;

__device__ __forceinline__ uint32_t pk2bf(float v0, float v1) {
    __hip_bfloat162 h = __float22bfloat162_rn(make_float2(v0, v1));  // v_cvt_pk_bf16_f32
    uint32_t u;
    __builtin_memcpy(&u, &h, 4);
    return u;
}

// ---------------------------------------------------------------------------
// Kernel 1: w_deform (COUT x CIN x 9 fp32) -> bf16, blocked [my][kb][o%128][8]
// K-order is kk-major: k' = kk*256 + c  (must match sampler's S layout)
// ---------------------------------------------------------------------------
__global__ __launch_bounds__(256) void prep_A(const float* __restrict__ wd,
                                              uint16_t* __restrict__ Ablk) {
    int t  = blockIdx.x * 256 + threadIdx.x;   // 73728 = 256*288
    int kb = t % KB;
    int o  = t / KB;
    int kkA = kb >> 5;            // (kb*8)/256
    int c0A = (kb & 31) * 8;      // (kb*8)%256
    const float* src = wd + (size_t)o * KTOT + c0A * KK + kkA;
    float a[8];
#pragma unroll
    for (int e = 0; e < 8; ++e) a[e] = src[e * KK];
    int my = o >> 7, ol = o & 127;
    uint16_t* dst = Ablk + (((size_t)my * KB + kb) * 128 + ol) * 8;
    u32x4 v;
    v.x = pk2bf(a[0], a[1]);
    v.y = pk2bf(a[2], a[3]);
    v.z = pk2bf(a[4], a[5]);
    v.w = pk2bf(a[6], a[7]);
    *(u32x4*)dst = v;
}

// ---------------------------------------------------------------------------
// Kernel 2: offsets + bilinear sampling -> S[b][kb][p][8] bf16 (kk-major K)
// block = 8x8 pixel tile x 32 channels, 256 thr; wave wv owns 8 channels ->
// ONE ch8 pass per kk. Window 32x12x12 fp32 = 18.4 KB LDS -> 8 blocks/CU
// (cap 32 waves/CU, 2x round-2) for LDS-latency hiding. woff read via
// wave-uniform global loads (s_load). In-loop clamp-aware separable weights
// (equivalent to reference's 4-corner valid-masked bilinear). Global
// fallback for offsets escaping the +-2 guard band (never taken here).
// ---------------------------------------------------------------------------
__global__ __launch_bounds__(256) void sampler(const float* __restrict__ feature,
                                               const float* __restrict__ pred,
                                               const float* __restrict__ woff,
                                               uint16_t* __restrict__ S) {
    __shared__ float ft[SCH * WIN * WIN];  // 18432 B

    int tid = threadIdx.x;
    int cb = blockIdx.y, b = blockIdx.z;
    int ch0 = cb * SCH;                    // global channel base
    int g = ch0 >> 6;                      // group
    int ty = blockIdx.x / (WW / TS), tx = blockIdx.x % (WW / TS);
    int r0 = ty * TS, c0 = tx * TS;
    int rlo = min(max(r0 - 2, 0), HH - WIN);
    int clo = min(max(c0 - 2, 0), WW - WIN);

    // ---- stage feature window [ch][r][q] (fp32), 4608 elems / 256 thr
    const float* fg = feature + ((size_t)(b * CIN + ch0)) * HW;
    for (int e = tid; e < SCH * WIN * WIN; e += 256) {
        int ch = e / (WIN * WIN);
        int re = e - ch * (WIN * WIN);
        int rr = re / WIN, cc = re - rr * WIN;
        ft[e] = fg[(size_t)ch * HW + (rlo + rr) * WW + clo + cc];
    }
    __syncthreads();

    int lane = tid & 63, wv = tid >> 6;    // wv in {0..3}: channels wv*8..+8
    int lr = lane >> 3, lc = lane & 7;
    int hy = r0 + lr, hx = c0 + lc;
    int p = hy * WW + hx;
    float4 ps4 = *(const float4*)(pred + ((size_t)b * HW + p) * 4);

    const float* ftw = ft + (wv * 8) * (WIN * WIN);
    const float* fgw = fg + (size_t)(wv * 8) * HW;      // fallback base
    int kb_base = cb * 4 + wv;             // (ch0 + wv*8)/8

#pragma unroll
    for (int kk = 0; kk < KK; ++kk) {
        const float* wy = woff + (g * KK + kk) * 8;     // uniform -> s_load
        float offy = ps4.x * wy[0] + ps4.y * wy[1] + ps4.z * wy[2] + ps4.w * wy[3];
        float offx = ps4.x * wy[4] + ps4.y * wy[5] + ps4.z * wy[6] + ps4.w * wy[7];
        float py = (float)(hy - 1 + kk / 3) + offy;
        float px = (float)(hx - 1 + kk % 3) + offx;
        float fy = floorf(py), fx = floorf(px);
        int y0 = (int)fy, x0 = (int)fx;
        float ly = py - fy, lx = px - fx;
        int r = min(max(y0, 0), HH - 2);
        int q = min(max(x0, 0), WW - 2);
        float wyA = (y0 == r) ? (1.f - ly) : ((y0 == -1) ? ly : 0.f);
        float wyB = (y0 == r) ? ly : ((y0 == HH - 1) ? (1.f - ly) : 0.f);
        float wxA = (x0 == q) ? (1.f - lx) : ((x0 == -1) ? lx : 0.f);
        float wxB = (x0 == q) ? lx : ((x0 == WW - 1) ? (1.f - lx) : 0.f);
        float c00 = wyA * wxA, c01 = wyA * wxB;
        float c10 = wyB * wxA, c11 = wyB * wxB;

        bool fast = (r >= rlo) & (r <= rlo + WIN - 2) &
                    (q >= clo) & (q <= clo + WIN - 2);

        uint16_t* Sp = S + (((size_t)b * KB + (kk * 32 + kb_base)) * HW + p) * 8;
        uint32_t pk[4];

        if (fast) {
            int base = (r - rlo) * WIN + (q - clo);
#pragma unroll
            for (int ep = 0; ep < 4; ++ep) {
                const float* f0 = ftw + (2 * ep) * (WIN * WIN) + base;
                const float* f1 = f0 + (WIN * WIN);
                float v0 = c00 * f0[0] + c01 * f0[1] + c10 * f0[WIN] + c11 * f0[WIN + 1];
                float v1 = c00 * f1[0] + c01 * f1[1] + c10 * f1[WIN] + c11 * f1[WIN + 1];
                pk[ep] = pk2bf(v0, v1);
            }
        } else {
            size_t gb = (size_t)r * WW + q;
#pragma unroll
            for (int ep = 0; ep < 4; ++ep) {
                const float* f0 = fgw + (size_t)(2 * ep) * HW + gb;
                const float* f1 = f0 + HW;
                float v0 = c00 * f0[0] + c01 * f0[1] + c10 * f0[WW] + c11 * f0[WW + 1];
                float v1 = c00 * f1[0] + c01 * f1[1] + c10 * f1[WW] + c11 * f1[WW + 1];
                pk[ep] = pk2bf(v0, v1);
            }
        }
        u32x4 vv = {pk[0], pk[1], pk[2], pk[3]};
        *(u32x4*)(Sp) = vv;
    }
}

// ---------------------------------------------------------------------------
// Kernel 3: out[b,o,p] = relu( sum_k A[o,k] * S[k,p] )  (bf16 MFMA 16x16x32)
// 128x64 tile, 4 waves each 64x32. Depth-4 pipeline: quad-buffered LDS
// (48 KB, 3 blocks/CU); steady-state s_waitcnt vmcnt(9) keeps 3 future
// K-steps (9 global_load_lds) in flight -> ~900 cyc slack covers HBM latency.
// ---------------------------------------------------------------------------
__global__ __launch_bounds__(256) void gemm_kernel(const uint16_t* __restrict__ S,
                                                   const uint16_t* __restrict__ Ablk,
                                                   float* __restrict__ out) {
    __shared__ uint16_t sA[4][4 * 128 * 8];   // 8 KB per buf
    __shared__ uint16_t sB[4][4 * 64 * 8];    // 4 KB per buf

    int tid = threadIdx.x;
    int lane = tid & 63, wv = tid >> 6;
    int wr = wv >> 1, wc = wv & 1;
    int col0 = blockIdx.x * 64;            // p tile (144)
    int my   = blockIdx.y;                 // o tile (2)
    int b    = blockIdx.z;

    const uint16_t* Ag = Ablk + (size_t)my * KB * 128 * 8;
    const uint16_t* Bg = S    + (size_t)b  * KB * HW  * 8;

    f32x4 acc[4][2];
#pragma unroll
    for (int m = 0; m < 4; ++m)
#pragma unroll
        for (int n = 0; n < 2; ++n) acc[m][n] = (f32x4){0.f, 0.f, 0.f, 0.f};

    int kc = lane >> 4, il = lane & 15;
    const int NT = KTOT / 32;              // 72

    // wave wv stages k-chunk row (t*4 + wv): A = 2 loads, B = 1 load
    auto STAGE = [&](int t, int buf) {
        const uint16_t* ga = Ag + ((size_t)(t * 4 + wv) * 128) * 8;
        uint16_t* la = &sA[buf][wv * 128 * 8];
#pragma unroll
        for (int h = 0; h < 2; ++h) {
            __builtin_amdgcn_global_load_lds(
                (const __attribute__((address_space(1))) uint32_t*)(ga + (h * 64 + lane) * 8),
                (__attribute__((address_space(3))) uint32_t*)(la + h * 64 * 8),
                16, 0, 0);
        }
        const uint16_t* gb = Bg + ((size_t)(t * 4 + wv) * HW + col0) * 8;
        uint16_t* lb = &sB[buf][wv * 64 * 8];
        __builtin_amdgcn_global_load_lds(
            (const __attribute__((address_space(1))) uint32_t*)(gb + lane * 8),
            (__attribute__((address_space(3))) uint32_t*)(lb),
            16, 0, 0);
    };

    STAGE(0, 0);
    STAGE(1, 1);
    STAGE(2, 2);
    STAGE(3, 3);

    for (int t = 0; t < NT; ++t) {
        int cur = t & 3;
        // wait for step t's loads; future stages' loads stay in flight
        if (t < NT - 3) {
            asm volatile("s_waitcnt vmcnt(9)\n\ts_barrier" ::: "memory");
        } else if (t == NT - 3) {
            asm volatile("s_waitcnt vmcnt(6)\n\ts_barrier" ::: "memory");
        } else if (t == NT - 2) {
            asm volatile("s_waitcnt vmcnt(3)\n\ts_barrier" ::: "memory");
        } else {
            asm volatile("s_waitcnt vmcnt(0)\n\ts_barrier" ::: "memory");
        }
        __builtin_amdgcn_sched_barrier(0);

        short8 af[4], bf[2];
#pragma unroll
        for (int m = 0; m < 4; ++m)
            af[m] = *(const short8*)(&sA[cur][((kc * 128) + (wr * 64 + m * 16 + il)) * 8]);
#pragma unroll
        for (int n = 0; n < 2; ++n)
            bf[n] = *(const short8*)(&sB[cur][((kc * 64) + (wc * 32 + n * 16 + il)) * 8]);

#pragma unroll
        for (int m = 0; m < 4; ++m)
#pragma unroll
            for (int n = 0; n < 2; ++n)
                acc[m][n] = __builtin_amdgcn_mfma_f32_16x16x32_bf16(af[m], bf[n], acc[m][n], 0, 0, 0);

        // all waves done reading buf[cur], then refill it for step t+4
        asm volatile("s_waitcnt lgkmcnt(0)\n\ts_barrier" ::: "memory");
        __builtin_amdgcn_sched_barrier(0);
        if (t + 4 < NT) STAGE(t + 4, cur);
    }

    int r4 = (lane >> 4) * 4;
    size_t obase = ((size_t)b * COUT + my * 128 + wr * 64) * HW + col0 + wc * 32;
#pragma unroll
    for (int m = 0; m < 4; ++m)
#pragma unroll
        for (int n = 0; n < 2; ++n)
#pragma unroll
            for (int r = 0; r < 4; ++r) {
                float v = acc[m][n][r];
                v = v > 0.f ? v : 0.f;
                out[obase + (size_t)(m * 16 + r4 + r) * HW + n * 16 + il] = v;
            }
}

// ---------------------------------------------------------------------------
extern "C" void kernel_launch(void* const* d_in, const int* in_sizes, int n_in,
                              void* d_out, int out_size, void* d_ws, size_t ws_size,
                              hipStream_t stream) {
    (void)in_sizes; (void)n_in; (void)out_size; (void)ws_size;
    const float* feature = (const float*)d_in[0];
    const float* pred    = (const float*)d_in[1];
    const float* woff    = (const float*)d_in[2];
    const float* wdef    = (const float*)d_in[3];
    float* out = (float*)d_out;

    const size_t S_BYTES = (size_t)NB * KB * HW * 8 * 2;   // 84,934,656
    uint16_t* S    = (uint16_t*)d_ws;
    uint16_t* Ablk = (uint16_t*)((char*)d_ws + S_BYTES);

    hipLaunchKernelGGL(prep_A, dim3(288), dim3(256), 0, stream, wdef, Ablk);
    hipLaunchKernelGGL(sampler, dim3((HH / TS) * (WW / TS), CIN / SCH, NB), dim3(256), 0, stream,
                       feature, pred, woff, S);
    hipLaunchKernelGGL(gemm_kernel, dim3(HW / 64, 2, NB), dim3(256), 0, stream,
                       S, Ablk, out);
}